// Round 7
// baseline (2603.434 us; speedup 1.0000x reference)
//
#include <hip/hip_runtime.h>

#define NN 400000
#define EE 1600000
#define NB 8192

typedef float vf4 __attribute__((ext_vector_type(4)));
typedef float vf2 __attribute__((ext_vector_type(2)));

// ---------- segment bounds: start[b] = lower_bound(batch, b); batch is sorted ----------
__global__ void k_seg(const int* __restrict__ batch, int* __restrict__ start){
  int b = blockIdx.x*256 + threadIdx.x;
  if (b > NB) return;
  int lo = 0, hi = NN;
  while (lo < hi){ int mid = (lo+hi)>>1; if (batch[mid] < b) lo = mid+1; else hi = mid; }
  start[b] = lo;
}

// ---------- gate MLP as tiled GEMM: 64 rows/block, 4x4 micro-tile; 2nd layer fused ----------
__global__ __launch_bounds__(256) void k_gate(const float* __restrict__ x,
    const float* __restrict__ W1, const float* __restrict__ b1,
    const float* __restrict__ W2, const float* __restrict__ b2,
    float* __restrict__ g){
  __shared__ __align__(16) float sX[64*68];    // [k][r] transposed, pad 68
  __shared__ __align__(16) float sW[64*64];    // W1 [k][c]
  __shared__ float sB[128];      // b1 | W2
  __shared__ float sRed[64*17];  // per-row partials
  const int tid = threadIdx.x;
  const int r0 = blockIdx.x << 6;
  for (int i = tid; i < 4096; i += 256) sW[i] = W1[i];
  if (tid < 64) sB[tid] = b1[tid];
  else if (tid < 128) sB[tid] = W2[tid-64];
  for (int i = tid; i < 4096; i += 256){     // coalesced read of 64x64 tile
    int r = i >> 6, k = i & 63;
    sX[k*68 + r] = x[(size_t)r0*64 + i];
  }
  __syncthreads();
  const int tx = tid & 15;   // cols tx*4..+3
  const int ty = tid >> 4;   // rows ty*4..+3
  float acc[4][4];
  #pragma unroll
  for (int i = 0; i < 4; ++i)
    #pragma unroll
    for (int j = 0; j < 4; ++j) acc[i][j] = 0.f;
  for (int k = 0; k < 64; ++k){
    vf4 a = *(const vf4*)&sX[k*68 + ty*4];   // ds_read_b128 broadcast, conflict-free
    vf4 w = *(const vf4*)&sW[k*64 + tx*4];
    #pragma unroll
    for (int i = 0; i < 4; ++i)
      #pragma unroll
      for (int j = 0; j < 4; ++j)
        acc[i][j] = fmaf(a[i], w[j], acc[i][j]);
  }
  #pragma unroll
  for (int i = 0; i < 4; ++i){
    float p = 0.f;
    #pragma unroll
    for (int j = 0; j < 4; ++j){
      int c = tx*4 + j;
      p = fmaf(fmaxf(acc[i][j] + sB[c], 0.f), sB[64+c], p);
    }
    sRed[(ty*4+i)*17 + tx] = p;
  }
  __syncthreads();
  if (tid < 64){
    float s = 0.f;
    #pragma unroll
    for (int j = 0; j < 16; ++j) s += sRed[tid*17 + j];
    g[r0 + tid] = s + b2[0];
  }
}

// ---------- attention pool: one wave per graph (segments contiguous: batch sorted) ----------
__global__ __launch_bounds__(64) void k_att(const float* __restrict__ x, const float* __restrict__ g,
    const int* __restrict__ start, float* __restrict__ att){
  int b = blockIdx.x, lane = threadIdx.x;
  int s0 = start[b], s1 = start[b+1];
  if (s1 <= s0){ att[b*64+lane] = 0.f; return; }
  float m = -3.0e38f;
  for (int i = s0+lane; i < s1; i += 64) m = fmaxf(m, g[i]);
  #pragma unroll
  for (int off = 32; off; off >>= 1) m = fmaxf(m, __shfl_xor(m, off));
  float s = 0.f;
  for (int i = s0+lane; i < s1; i += 64) s += expf(g[i]-m);
  #pragma unroll
  for (int off = 32; off; off >>= 1) s += __shfl_xor(s, off);
  float acc = 0.f;
  for (int i = s0; i < s1; ++i)                       // lane = feature
    acc = fmaf(expf(g[i]-m), x[(size_t)i*64+lane], acc);
  att[b*64+lane] = acc / s;
}

// ---------- CSR build (per side, reused for all 3 layers) ----------
__global__ void k_zero(int* __restrict__ degI, int* __restrict__ gc){
  int i = blockIdx.x*256 + threadIdx.x;
  if (i < NN) degI[i] = 0;
  if (i == 0) *gc = 0;
}
__global__ void k_count(const int* __restrict__ dst, int* __restrict__ degI){
  int e = blockIdx.x*256 + threadIdx.x;
  if (e < EE) atomicAdd(&degI[dst[e]], 1);
}
// bucket allocation: wave-level prefix scan, one global atomic per wave
__global__ __launch_bounds__(256) void k_alloc(const int* __restrict__ degI, int* __restrict__ gc,
    int* __restrict__ base, int* __restrict__ cursor, float* __restrict__ dinv){
  int i = blockIdx.x*256 + threadIdx.x;
  int lane = threadIdx.x & 63;
  int d = (i < NN) ? degI[i] : 0;
  int incl = d;
  #pragma unroll
  for (int off = 1; off < 64; off <<= 1){
    int t = __shfl_up(incl, off);
    if (lane >= off) incl += t;
  }
  int waveTotal = __shfl(incl, 63);
  int wbase = 0;
  if (lane == 63) wbase = atomicAdd(gc, waveTotal);
  wbase = __shfl(wbase, 63);
  if (i < NN){
    int b = wbase + incl - d;   // exclusive offset within wave
    base[i] = b; cursor[i] = b;
    dinv[i] = 1.f / sqrtf((float)d + 1.f);   // +1 self loop
  }
}
// csr2[p] = {src, dinv[src]} -- weight folded in so gathers skip the dinv lookup
__global__ void k_fillcsr(const int* __restrict__ src, const int* __restrict__ dst,
                          const float* __restrict__ dinv,
                          int* __restrict__ cursor, int2* __restrict__ csr2){
  int e = blockIdx.x*256 + threadIdx.x;
  if (e >= EE) return;
  int s = src[e];
  int p = atomicAdd(&cursor[dst[e]], 1);
  csr2[p] = make_int2(s, __float_as_int(dinv[s]));
}

// ---------- tall-skinny GEMM: out[N,96] = act(in[N,K] @ W[K,96] + b) ----------
// 512 threads/block (was 256): same 64x96 tile + 63KB LDS -> still 2 blocks/CU,
// but 16 waves/CU = 4 waves/SIMD (was 2) to hide ds_read latency (R6: VALU 49%,
// occ 20% = latency-bound). Micro-tile 4 rows x 3 cols. w reads: 3 scalar b32 at
// stride 3 (coprime 32) -> all lanes distinct banks, conflict-free.
template<int K, bool RELU>
__global__ __launch_bounds__(512) void k_gemm(const float* __restrict__ in,
    const float* __restrict__ W, const float* __restrict__ bias, float* __restrict__ out){
  __shared__ __align__(16) float sIn[K*68];   // transposed [k][row], pad 68 (272B = 17*16)
  __shared__ __align__(16) float sW[K*96];
  __shared__ float sB[96];
  const int tid = threadIdx.x;
  const int r0 = blockIdx.x << 6;
  for (int i = tid; i < K*96; i += 512) sW[i] = W[i];
  if (tid < 96) sB[tid] = bias[tid];
  for (int i = tid; i < 64*K; i += 512){
    int r = i / K, k = i - r*K;
    sIn[k*68 + r] = in[(size_t)r0*K + i];
  }
  __syncthreads();
  const int tx = tid & 31;   // cols tx*3 .. +2
  const int ty = tid >> 5;   // rows ty*4 .. +3
  float acc[4][3];
  #pragma unroll
  for (int i = 0; i < 4; ++i)
    #pragma unroll
    for (int j = 0; j < 3; ++j) acc[i][j] = 0.f;
  for (int k = 0; k < K; ++k){
    vf4 a = *(const vf4*)&sIn[k*68 + ty*4];   // b128, broadcast, conflict-free
    float w0 = sW[k*96 + tx*3];
    float w1 = sW[k*96 + tx*3 + 1];
    float w2 = sW[k*96 + tx*3 + 2];
    #pragma unroll
    for (int i = 0; i < 4; ++i){
      acc[i][0] = fmaf(a[i], w0, acc[i][0]);
      acc[i][1] = fmaf(a[i], w1, acc[i][1]);
      acc[i][2] = fmaf(a[i], w2, acc[i][2]);
    }
  }
  #pragma unroll
  for (int i = 0; i < 4; ++i){
    size_t row = r0 + ty*4 + i;
    #pragma unroll
    for (int j = 0; j < 3; ++j){
      float v = acc[i][j] + sB[tx*3 + j];
      if (RELU) v = fmaxf(v, 0.f);
      out[row*96 + tx*3 + j] = v;
    }
  }
}

// ---------- GCN aggregation (96 feats): agg[i] = di*(di*v[i] + sum_e w_e*v[src_e]) ----------
// Latency-bound -> 8-edge CLAMPED batch: always issue 8 metadata + 8 vf4 loads per
// iter; index clamped to cnt-1, weight zeroed for p>=cnt (clamped dups hit the same
// cache line, ~free). Avg degree 4 -> 98% of nodes need one iteration. (R6 win.)
__global__ __launch_bounds__(256) void k_gather96(const float* __restrict__ xw,
    const int2* __restrict__ csr2, const int* __restrict__ base, const int* __restrict__ degI,
    const float* __restrict__ dinv, float* __restrict__ out){
  const int grp  = threadIdx.x >> 5;        // 8 nodes per block
  const int lane = threadIdx.x & 31;        // lanes 0..23 carry float4 features
  const int i = (blockIdx.x << 3) + grp;
  const bool act = lane < 24;
  const vf4* __restrict__ xw4 = (const vf4*)xw;
  const float di = dinv[i];
  const int b0 = base[i], cnt = degI[i];
  vf4 s = {0.f,0.f,0.f,0.f};
  if (act) s = di * xw4[(size_t)i*24 + lane];
  for (int t = 0; t < cnt; t += 8){
    int2 e[8]; float w[8];
    #pragma unroll
    for (int k = 0; k < 8; ++k){
      int p = t + k;
      int q = p < cnt ? p : cnt-1;          // clamp (cnt>=1 inside loop)
      e[k] = csr2[b0 + q];
      w[k] = (p < cnt) ? __int_as_float(e[k].y) : 0.f;
    }
    if (act){
      #pragma unroll
      for (int k = 0; k < 8; ++k){
        vf4 v = xw4[(size_t)e[k].x*24 + lane];
        s += w[k]*v;
      }
    }
  }
  if (act){
    vf4 r = di * s;
    ((vf4*)out)[(size_t)i*24 + lane] = r;
  }
}

// ---------- GCN aggregation (64 feats, layer-0 reorder): agg0 = A_hat x ----------
// Same 8-edge clamped batch; 16 nodes/block, 16 lanes/node, all lanes active.
__global__ __launch_bounds__(256) void k_gather64(const float* __restrict__ x,
    const int2* __restrict__ csr2, const int* __restrict__ base, const int* __restrict__ degI,
    const float* __restrict__ dinv, float* __restrict__ out){
  const int grp  = threadIdx.x >> 4;        // 16 nodes per block
  const int lane = threadIdx.x & 15;        // 16 lanes x float4 = 64 feats
  const int i = (blockIdx.x << 4) + grp;
  const vf4* __restrict__ x4 = (const vf4*)x;
  const float di = dinv[i];
  const int b0 = base[i], cnt = degI[i];
  vf4 s = di * x4[(size_t)i*16 + lane];
  for (int t = 0; t < cnt; t += 8){
    int2 e[8]; float w[8];
    #pragma unroll
    for (int k = 0; k < 8; ++k){
      int p = t + k;
      int q = p < cnt ? p : cnt-1;
      e[k] = csr2[b0 + q];
      w[k] = (p < cnt) ? __int_as_float(e[k].y) : 0.f;
    }
    #pragma unroll
    for (int k = 0; k < 8; ++k){
      vf4 v = x4[(size_t)e[k].x*16 + lane];
      s += w[k]*v;
    }
  }
  vf4 r = di * s;
  ((vf4*)out)[(size_t)i*16 + lane] = r;
}

// ---------- mean pool ----------
__global__ __launch_bounds__(128) void k_mean(const float* __restrict__ h,
    const int* __restrict__ start, float* __restrict__ mean){
  int b = blockIdx.x, f = threadIdx.x;
  if (f >= 96) return;
  int s0 = start[b], s1 = start[b+1];
  float acc = 0.f;
  for (int i = s0; i < s1; ++i) acc += h[(size_t)i*96+f];
  mean[b*96+f] = acc / fmaxf((float)(s1-s0), 1.f);
}

// ---------- final MLP: relu(cat@W0+b0)@W1+b1 ; fp32 output ----------
__global__ __launch_bounds__(128) void k_final(const float* __restrict__ meanP, const float* __restrict__ meanD,
    const float* __restrict__ attP, const float* __restrict__ attD,
    const float* __restrict__ W0, const float* __restrict__ b0,
    const float* __restrict__ W1, const float* __restrict__ b1,
    float* __restrict__ out){
  __shared__ float cat[320];
  __shared__ float hb[96];
  int b = blockIdx.x, tid = threadIdx.x;
  if (tid < 96){ cat[tid] = meanP[b*96+tid]; cat[96+tid] = meanD[b*96+tid]; }
  if (tid < 64){ cat[192+tid] = attP[b*64+tid]; cat[256+tid] = attD[b*64+tid]; }
  __syncthreads();
  if (tid < 96){
    float acc = b0[tid];
    for (int k = 0; k < 320; ++k) acc = fmaf(cat[k], W0[k*96+tid], acc);
    hb[tid] = fmaxf(acc, 0.f) * W1[tid];
  }
  __syncthreads();
  if (tid == 0){
    float y = b1[0];
    for (int j = 0; j < 96; ++j) y += hb[j];
    out[b] = y;
  }
}

extern "C" void kernel_launch(void* const* d_in, const int* in_sizes, int n_in,
                              void* d_out, int out_size, void* d_ws, size_t ws_size,
                              hipStream_t stream){
  const float* x_p = (const float*)d_in[0];
  const float* x_d = (const float*)d_in[1];
  const int* ei_p = (const int*)d_in[4];    // [2,E]: row0 src, row1 dst
  const int* ei_d = (const int*)d_in[5];
  const int* batch_p = (const int*)d_in[6];
  const int* batch_d = (const int*)d_in[7];
  const float* gW1 = (const float*)d_in[8];
  const float* gb1 = (const float*)d_in[9];
  const float* gW2 = (const float*)d_in[10];
  const float* gb2 = (const float*)d_in[11];
  const float* cW[2][3] = {{(const float*)d_in[12],(const float*)d_in[14],(const float*)d_in[16]},
                           {(const float*)d_in[18],(const float*)d_in[20],(const float*)d_in[22]}};
  const float* cB[2][3] = {{(const float*)d_in[13],(const float*)d_in[15],(const float*)d_in[17]},
                           {(const float*)d_in[19],(const float*)d_in[21],(const float*)d_in[23]}};
  const float* lW0 = (const float*)d_in[24];
  const float* lb0 = (const float*)d_in[25];
  const float* lW1 = (const float*)d_in[26];
  const float* lb1 = (const float*)d_in[27];
  float* out = (float*)d_out;

  // workspace carve-up (~363 MB)
  float* fws = (float*)d_ws;
  size_t off = 0;
  float* A     = fws + off; off += (size_t)NN*96;   // agg buffer (64- or 96-dim)
  float* Bf    = fws + off; off += (size_t)NN*96;   // hidden buffer
  float* dinv  = fws + off; off += NN;
  float* g     = fws + off; off += NN;
  float* attP  = fws + off; off += (size_t)NB*64;
  float* attD  = fws + off; off += (size_t)NB*64;
  float* meanP = fws + off; off += (size_t)NB*96;
  float* meanD = fws + off; off += (size_t)NB*96;
  int2* csr2  = (int2*)(fws + off);                 // 8-byte aligned (off is even)
  int* iws = (int*)(csr2 + EE);
  int* segP   = iws;             iws += NB+1;
  int* segD   = iws;             iws += NB+1;
  int* degI   = iws;             iws += NN;
  int* base   = iws;             iws += NN;
  int* cursor = iws;             iws += NN;
  int* gc     = iws;             iws += 1;

  k_seg<<<(NB+1+255)/256, 256, 0, stream>>>(batch_p, segP);
  k_seg<<<(NB+1+255)/256, 256, 0, stream>>>(batch_d, segD);

  for (int side = 0; side < 2; ++side){
    const float* x  = side ? x_d : x_p;
    const int* src = side ? ei_d : ei_p;
    const int* dst = src + EE;
    const int* seg = side ? segD : segP;
    float* att  = side ? attD : attP;
    float* mean = side ? meanD : meanP;

    k_gate<<<NN/64, 256, 0, stream>>>(x, gW1, gb1, gW2, gb2, g);
    k_att<<<NB, 64, 0, stream>>>(x, g, seg, att);

    k_zero   <<<(NN+255)/256, 256, 0, stream>>>(degI, gc);
    k_count  <<<(EE+255)/256, 256, 0, stream>>>(dst, degI);
    k_alloc  <<<(NN+255)/256, 256, 0, stream>>>(degI, gc, base, cursor, dinv);
    k_fillcsr<<<(EE+255)/256, 256, 0, stream>>>(src, dst, dinv, cursor, csr2);

    // layer 0 reordered: agg0 = A_hat x (64-dim), then h1 = relu(agg0 @ W0 + b0)
    k_gather64<<<NN/16, 256, 0, stream>>>(x, csr2, base, degI, dinv, A);
    k_gemm<64,true ><<<NN/64, 512, 0, stream>>>(A, cW[side][0], cB[side][0], Bf);
    // layer 1: agg1 = A_hat h1, h2 = relu(agg1 @ W1 + b1)
    k_gather96<<<NN/8, 256, 0, stream>>>(Bf, csr2, base, degI, dinv, A);
    k_gemm<96,true ><<<NN/64, 512, 0, stream>>>(A, cW[side][1], cB[side][1], Bf);
    // layer 2: agg2 = A_hat h2, h3 = agg2 @ W2 + b2 (no relu)
    k_gather96<<<NN/8, 256, 0, stream>>>(Bf, csr2, base, degI, dinv, A);
    k_gemm<96,false><<<NN/64, 512, 0, stream>>>(A, cW[side][2], cB[side][2], Bf);

    k_mean<<<NB, 128, 0, stream>>>(Bf, seg, mean);
  }
  k_final<<<NB, 128, 0, stream>>>(meanP, meanD, attP, attD, lW0, lb0, lW1, lb1, out);
}

// Round 8
// 2285.278 us; speedup vs baseline: 1.1392x; 1.1392x over previous
//
#include <hip/hip_runtime.h>

#define NN 400000
#define EE 1600000
#define NB 8192

typedef float vf4 __attribute__((ext_vector_type(4)));
typedef float vf2 __attribute__((ext_vector_type(2)));

// ---------- segment bounds: start[b] = lower_bound(batch, b); batch is sorted ----------
__global__ void k_seg(const int* __restrict__ batch, int* __restrict__ start){
  int b = blockIdx.x*256 + threadIdx.x;
  if (b > NB) return;
  int lo = 0, hi = NN;
  while (lo < hi){ int mid = (lo+hi)>>1; if (batch[mid] < b) lo = mid+1; else hi = mid; }
  start[b] = lo;
}

// ---------- gate MLP as tiled GEMM: 64 rows/block, 4x4 micro-tile; 2nd layer fused ----------
__global__ __launch_bounds__(256) void k_gate(const float* __restrict__ x,
    const float* __restrict__ W1, const float* __restrict__ b1,
    const float* __restrict__ W2, const float* __restrict__ b2,
    float* __restrict__ g){
  __shared__ __align__(16) float sX[64*68];    // [k][r] transposed, pad 68
  __shared__ __align__(16) float sW[64*64];    // W1 [k][c]
  __shared__ float sB[128];      // b1 | W2
  __shared__ float sRed[64*17];  // per-row partials
  const int tid = threadIdx.x;
  const int r0 = blockIdx.x << 6;
  for (int i = tid; i < 4096; i += 256) sW[i] = W1[i];
  if (tid < 64) sB[tid] = b1[tid];
  else if (tid < 128) sB[tid] = W2[tid-64];
  for (int i = tid; i < 4096; i += 256){     // coalesced read of 64x64 tile
    int r = i >> 6, k = i & 63;
    sX[k*68 + r] = x[(size_t)r0*64 + i];
  }
  __syncthreads();
  const int tx = tid & 15;   // cols tx*4..+3
  const int ty = tid >> 4;   // rows ty*4..+3
  float acc[4][4];
  #pragma unroll
  for (int i = 0; i < 4; ++i)
    #pragma unroll
    for (int j = 0; j < 4; ++j) acc[i][j] = 0.f;
  for (int k = 0; k < 64; ++k){
    vf4 a = *(const vf4*)&sX[k*68 + ty*4];   // ds_read_b128 broadcast, conflict-free
    vf4 w = *(const vf4*)&sW[k*64 + tx*4];
    #pragma unroll
    for (int i = 0; i < 4; ++i)
      #pragma unroll
      for (int j = 0; j < 4; ++j)
        acc[i][j] = fmaf(a[i], w[j], acc[i][j]);
  }
  #pragma unroll
  for (int i = 0; i < 4; ++i){
    float p = 0.f;
    #pragma unroll
    for (int j = 0; j < 4; ++j){
      int c = tx*4 + j;
      p = fmaf(fmaxf(acc[i][j] + sB[c], 0.f), sB[64+c], p);
    }
    sRed[(ty*4+i)*17 + tx] = p;
  }
  __syncthreads();
  if (tid < 64){
    float s = 0.f;
    #pragma unroll
    for (int j = 0; j < 16; ++j) s += sRed[tid*17 + j];
    g[r0 + tid] = s + b2[0];
  }
}

// ---------- attention pool: one wave per graph (segments contiguous: batch sorted) ----------
__global__ __launch_bounds__(64) void k_att(const float* __restrict__ x, const float* __restrict__ g,
    const int* __restrict__ start, float* __restrict__ att){
  int b = blockIdx.x, lane = threadIdx.x;
  int s0 = start[b], s1 = start[b+1];
  if (s1 <= s0){ att[b*64+lane] = 0.f; return; }
  float m = -3.0e38f;
  for (int i = s0+lane; i < s1; i += 64) m = fmaxf(m, g[i]);
  #pragma unroll
  for (int off = 32; off; off >>= 1) m = fmaxf(m, __shfl_xor(m, off));
  float s = 0.f;
  for (int i = s0+lane; i < s1; i += 64) s += expf(g[i]-m);
  #pragma unroll
  for (int off = 32; off; off >>= 1) s += __shfl_xor(s, off);
  float acc = 0.f;
  for (int i = s0; i < s1; ++i)                       // lane = feature
    acc = fmaf(expf(g[i]-m), x[(size_t)i*64+lane], acc);
  att[b*64+lane] = acc / s;
}

// ---------- CSR build (per side, reused for all 3 layers) ----------
__global__ void k_zero(int* __restrict__ degI, int* __restrict__ gc){
  int i = blockIdx.x*256 + threadIdx.x;
  if (i < NN) degI[i] = 0;
  if (i == 0) *gc = 0;
}
__global__ void k_count(const int* __restrict__ dst, int* __restrict__ degI){
  int e = blockIdx.x*256 + threadIdx.x;
  if (e < EE) atomicAdd(&degI[dst[e]], 1);
}
// bucket allocation: wave-level prefix scan, one global atomic per wave
__global__ __launch_bounds__(256) void k_alloc(const int* __restrict__ degI, int* __restrict__ gc,
    int* __restrict__ base, int* __restrict__ cursor, float* __restrict__ dinv){
  int i = blockIdx.x*256 + threadIdx.x;
  int lane = threadIdx.x & 63;
  int d = (i < NN) ? degI[i] : 0;
  int incl = d;
  #pragma unroll
  for (int off = 1; off < 64; off <<= 1){
    int t = __shfl_up(incl, off);
    if (lane >= off) incl += t;
  }
  int waveTotal = __shfl(incl, 63);
  int wbase = 0;
  if (lane == 63) wbase = atomicAdd(gc, waveTotal);
  wbase = __shfl(wbase, 63);
  if (i < NN){
    int b = wbase + incl - d;   // exclusive offset within wave
    base[i] = b; cursor[i] = b;
    dinv[i] = 1.f / sqrtf((float)d + 1.f);   // +1 self loop
  }
}
// csr2[p] = {src, dinv[src]} -- weight folded in so gathers skip the dinv lookup
__global__ void k_fillcsr(const int* __restrict__ src, const int* __restrict__ dst,
                          const float* __restrict__ dinv,
                          int* __restrict__ cursor, int2* __restrict__ csr2){
  int e = blockIdx.x*256 + threadIdx.x;
  if (e >= EE) return;
  int s = src[e];
  int p = atomicAdd(&cursor[dst[e]], 1);
  csr2[p] = make_int2(s, __float_as_int(dinv[s]));
}

// ---------- tall-skinny GEMM: out[N,96] = act(in[N,K] @ W[K,96] + b) ----------
// R6-verified structure (153us): 256 threads, full-K staging, 4x6 micro-tile,
// vectorized LDS reads. 512-thread variant proven WORSE (R7: +60% issue cycles).
template<int K, bool RELU>
__global__ __launch_bounds__(256) void k_gemm(const float* __restrict__ in,
    const float* __restrict__ W, const float* __restrict__ bias, float* __restrict__ out){
  __shared__ __align__(16) float sIn[K*68];   // transposed [k][row], pad 68 (272B = 17*16)
  __shared__ __align__(16) float sW[K*96];
  __shared__ float sB[96];
  const int tid = threadIdx.x;
  const int r0 = blockIdx.x << 6;
  for (int i = tid; i < K*96; i += 256) sW[i] = W[i];
  if (tid < 96) sB[tid] = bias[tid];
  for (int i = tid; i < 64*K; i += 256){
    int r = i / K, k = i - r*K;
    sIn[k*68 + r] = in[(size_t)r0*K + i];
  }
  __syncthreads();
  const int tx = tid & 15;   // cols tx*6 .. +5
  const int ty = tid >> 4;   // rows ty*4 .. +3
  float acc[4][6];
  #pragma unroll
  for (int i = 0; i < 4; ++i)
    #pragma unroll
    for (int j = 0; j < 6; ++j) acc[i][j] = 0.f;
  for (int k = 0; k < K; ++k){
    vf4 a   = *(const vf4*)&sIn[k*68 + ty*4];       // b128, broadcast, conflict-free
    vf2 w01 = *(const vf2*)&sW[k*96 + tx*6];        // 3x b64, step 6 covers 32 banks
    vf2 w23 = *(const vf2*)&sW[k*96 + tx*6 + 2];
    vf2 w45 = *(const vf2*)&sW[k*96 + tx*6 + 4];
    float w[6] = {w01[0], w01[1], w23[0], w23[1], w45[0], w45[1]};
    #pragma unroll
    for (int i = 0; i < 4; ++i)
      #pragma unroll
      for (int j = 0; j < 6; ++j)
        acc[i][j] = fmaf(a[i], w[j], acc[i][j]);
  }
  #pragma unroll
  for (int i = 0; i < 4; ++i){
    size_t row = r0 + ty*4 + i;
    #pragma unroll
    for (int j = 0; j < 6; ++j){
      float v = acc[i][j] + sB[tx*6 + j];
      if (RELU) v = fmaxf(v, 0.f);
      out[row*96 + tx*6 + j] = v;
    }
  }
}

// ---------- pooled GEMM (layer-2 commute): mean [NB,96] @ W2 + b2, empty-seg masked ----------
// mean_pool(A_hat h W + 1 b^T) = mean_pool(A_hat h) @ W + b (layer 2 has no relu)
// -> the N-row layer-2 GEMM collapses to an 8192-row one. Empty segments must give
// 0 (reference semantics), not b2, hence the start[] mask.
__global__ __launch_bounds__(256) void k_gemm_pool(const float* __restrict__ in,
    const float* __restrict__ W, const float* __restrict__ bias,
    const int* __restrict__ start, float* __restrict__ out){
  constexpr int K = 96;
  __shared__ __align__(16) float sIn[K*68];
  __shared__ __align__(16) float sW[K*96];
  __shared__ float sB[96];
  const int tid = threadIdx.x;
  const int r0 = blockIdx.x << 6;
  for (int i = tid; i < K*96; i += 256) sW[i] = W[i];
  if (tid < 96) sB[tid] = bias[tid];
  for (int i = tid; i < 64*K; i += 256){
    int r = i / K, k = i - r*K;
    sIn[k*68 + r] = in[(size_t)r0*K + i];
  }
  __syncthreads();
  const int tx = tid & 15;
  const int ty = tid >> 4;
  float acc[4][6];
  #pragma unroll
  for (int i = 0; i < 4; ++i)
    #pragma unroll
    for (int j = 0; j < 6; ++j) acc[i][j] = 0.f;
  for (int k = 0; k < K; ++k){
    vf4 a   = *(const vf4*)&sIn[k*68 + ty*4];
    vf2 w01 = *(const vf2*)&sW[k*96 + tx*6];
    vf2 w23 = *(const vf2*)&sW[k*96 + tx*6 + 2];
    vf2 w45 = *(const vf2*)&sW[k*96 + tx*6 + 4];
    float w[6] = {w01[0], w01[1], w23[0], w23[1], w45[0], w45[1]};
    #pragma unroll
    for (int i = 0; i < 4; ++i)
      #pragma unroll
      for (int j = 0; j < 6; ++j)
        acc[i][j] = fmaf(a[i], w[j], acc[i][j]);
  }
  #pragma unroll
  for (int i = 0; i < 4; ++i){
    int row = r0 + ty*4 + i;
    bool nz = start[row+1] > start[row];
    #pragma unroll
    for (int j = 0; j < 6; ++j){
      float v = nz ? (acc[i][j] + sB[tx*6 + j]) : 0.f;
      out[(size_t)row*96 + tx*6 + j] = v;
    }
  }
}

// ---------- GCN aggregation (96 feats): agg[i] = di*(di*v[i] + sum_e w_e*v[src_e]) ----------
// Latency-bound -> 8-edge CLAMPED batch (R6 win): always issue 8 metadata + 8 vf4
// loads per iter; index clamped to cnt-1, weight zeroed for p>=cnt.
__global__ __launch_bounds__(256) void k_gather96(const float* __restrict__ xw,
    const int2* __restrict__ csr2, const int* __restrict__ base, const int* __restrict__ degI,
    const float* __restrict__ dinv, float* __restrict__ out){
  const int grp  = threadIdx.x >> 5;        // 8 nodes per block
  const int lane = threadIdx.x & 31;        // lanes 0..23 carry float4 features
  const int i = (blockIdx.x << 3) + grp;
  const bool act = lane < 24;
  const vf4* __restrict__ xw4 = (const vf4*)xw;
  const float di = dinv[i];
  const int b0 = base[i], cnt = degI[i];
  vf4 s = {0.f,0.f,0.f,0.f};
  if (act) s = di * xw4[(size_t)i*24 + lane];
  for (int t = 0; t < cnt; t += 8){
    int2 e[8]; float w[8];
    #pragma unroll
    for (int k = 0; k < 8; ++k){
      int p = t + k;
      int q = p < cnt ? p : cnt-1;          // clamp (cnt>=1 inside loop)
      e[k] = csr2[b0 + q];
      w[k] = (p < cnt) ? __int_as_float(e[k].y) : 0.f;
    }
    if (act){
      #pragma unroll
      for (int k = 0; k < 8; ++k){
        vf4 v = xw4[(size_t)e[k].x*24 + lane];
        s += w[k]*v;
      }
    }
  }
  if (act){
    vf4 r = di * s;
    ((vf4*)out)[(size_t)i*24 + lane] = r;
  }
}

// ---------- GCN aggregation (64 feats, layer-0 reorder): agg0 = A_hat x ----------
__global__ __launch_bounds__(256) void k_gather64(const float* __restrict__ x,
    const int2* __restrict__ csr2, const int* __restrict__ base, const int* __restrict__ degI,
    const float* __restrict__ dinv, float* __restrict__ out){
  const int grp  = threadIdx.x >> 4;        // 16 nodes per block
  const int lane = threadIdx.x & 15;        // 16 lanes x float4 = 64 feats
  const int i = (blockIdx.x << 4) + grp;
  const vf4* __restrict__ x4 = (const vf4*)x;
  const float di = dinv[i];
  const int b0 = base[i], cnt = degI[i];
  vf4 s = di * x4[(size_t)i*16 + lane];
  for (int t = 0; t < cnt; t += 8){
    int2 e[8]; float w[8];
    #pragma unroll
    for (int k = 0; k < 8; ++k){
      int p = t + k;
      int q = p < cnt ? p : cnt-1;
      e[k] = csr2[b0 + q];
      w[k] = (p < cnt) ? __int_as_float(e[k].y) : 0.f;
    }
    #pragma unroll
    for (int k = 0; k < 8; ++k){
      vf4 v = x4[(size_t)e[k].x*16 + lane];
      s += w[k]*v;
    }
  }
  vf4 r = di * s;
  ((vf4*)out)[(size_t)i*16 + lane] = r;
}

// ---------- mean pool ----------
__global__ __launch_bounds__(128) void k_mean(const float* __restrict__ h,
    const int* __restrict__ start, float* __restrict__ mean){
  int b = blockIdx.x, f = threadIdx.x;
  if (f >= 96) return;
  int s0 = start[b], s1 = start[b+1];
  float acc = 0.f;
  for (int i = s0; i < s1; ++i) acc += h[(size_t)i*96+f];
  mean[b*96+f] = acc / fmaxf((float)(s1-s0), 1.f);
}

// ---------- final MLP: relu(cat@W0+b0)@W1+b1 ; fp32 output ----------
__global__ __launch_bounds__(128) void k_final(const float* __restrict__ meanP, const float* __restrict__ meanD,
    const float* __restrict__ attP, const float* __restrict__ attD,
    const float* __restrict__ W0, const float* __restrict__ b0,
    const float* __restrict__ W1, const float* __restrict__ b1,
    float* __restrict__ out){
  __shared__ float cat[320];
  __shared__ float hb[96];
  int b = blockIdx.x, tid = threadIdx.x;
  if (tid < 96){ cat[tid] = meanP[b*96+tid]; cat[96+tid] = meanD[b*96+tid]; }
  if (tid < 64){ cat[192+tid] = attP[b*64+tid]; cat[256+tid] = attD[b*64+tid]; }
  __syncthreads();
  if (tid < 96){
    float acc = b0[tid];
    for (int k = 0; k < 320; ++k) acc = fmaf(cat[k], W0[k*96+tid], acc);
    hb[tid] = fmaxf(acc, 0.f) * W1[tid];
  }
  __syncthreads();
  if (tid == 0){
    float y = b1[0];
    for (int j = 0; j < 96; ++j) y += hb[j];
    out[b] = y;
  }
}

extern "C" void kernel_launch(void* const* d_in, const int* in_sizes, int n_in,
                              void* d_out, int out_size, void* d_ws, size_t ws_size,
                              hipStream_t stream){
  const float* x_p = (const float*)d_in[0];
  const float* x_d = (const float*)d_in[1];
  const int* ei_p = (const int*)d_in[4];    // [2,E]: row0 src, row1 dst
  const int* ei_d = (const int*)d_in[5];
  const int* batch_p = (const int*)d_in[6];
  const int* batch_d = (const int*)d_in[7];
  const float* gW1 = (const float*)d_in[8];
  const float* gb1 = (const float*)d_in[9];
  const float* gW2 = (const float*)d_in[10];
  const float* gb2 = (const float*)d_in[11];
  const float* cW[2][3] = {{(const float*)d_in[12],(const float*)d_in[14],(const float*)d_in[16]},
                           {(const float*)d_in[18],(const float*)d_in[20],(const float*)d_in[22]}};
  const float* cB[2][3] = {{(const float*)d_in[13],(const float*)d_in[15],(const float*)d_in[17]},
                           {(const float*)d_in[19],(const float*)d_in[21],(const float*)d_in[23]}};
  const float* lW0 = (const float*)d_in[24];
  const float* lb0 = (const float*)d_in[25];
  const float* lW1 = (const float*)d_in[26];
  const float* lb1 = (const float*)d_in[27];
  float* out = (float*)d_out;

  // workspace carve-up (~366 MB)
  float* fws = (float*)d_ws;
  size_t off = 0;
  float* A     = fws + off; off += (size_t)NN*96;   // agg buffer (64- or 96-dim)
  float* Bf    = fws + off; off += (size_t)NN*96;   // hidden buffer
  float* dinv  = fws + off; off += NN;
  float* g     = fws + off; off += NN;
  float* attP  = fws + off; off += (size_t)NB*64;
  float* attD  = fws + off; off += (size_t)NB*64;
  float* meanP = fws + off; off += (size_t)NB*96;
  float* meanD = fws + off; off += (size_t)NB*96;
  float* poolT = fws + off; off += (size_t)NB*96;   // pooled pre-W2 buffer
  int2* csr2  = (int2*)(fws + off);                 // 8-byte aligned (off is even)
  int* iws = (int*)(csr2 + EE);
  int* segP   = iws;             iws += NB+1;
  int* segD   = iws;             iws += NB+1;
  int* degI   = iws;             iws += NN;
  int* base   = iws;             iws += NN;
  int* cursor = iws;             iws += NN;
  int* gc     = iws;             iws += 1;

  k_seg<<<(NB+1+255)/256, 256, 0, stream>>>(batch_p, segP);
  k_seg<<<(NB+1+255)/256, 256, 0, stream>>>(batch_d, segD);

  for (int side = 0; side < 2; ++side){
    const float* x  = side ? x_d : x_p;
    const int* src = side ? ei_d : ei_p;
    const int* dst = src + EE;
    const int* seg = side ? segD : segP;
    float* att  = side ? attD : attP;
    float* mean = side ? meanD : meanP;

    k_gate<<<NN/64, 256, 0, stream>>>(x, gW1, gb1, gW2, gb2, g);
    k_att<<<NB, 64, 0, stream>>>(x, g, seg, att);

    k_zero   <<<(NN+255)/256, 256, 0, stream>>>(degI, gc);
    k_count  <<<(EE+255)/256, 256, 0, stream>>>(dst, degI);
    k_alloc  <<<(NN+255)/256, 256, 0, stream>>>(degI, gc, base, cursor, dinv);
    k_fillcsr<<<(EE+255)/256, 256, 0, stream>>>(src, dst, dinv, cursor, csr2);

    // layer 0 reordered: agg0 = A_hat x (64-dim), then h1 = relu(agg0 @ W0 + b0)
    k_gather64<<<NN/16, 256, 0, stream>>>(x, csr2, base, degI, dinv, A);
    k_gemm<64,true ><<<NN/64, 256, 0, stream>>>(A, cW[side][0], cB[side][0], Bf);
    // layer 1: agg1 = A_hat h1, h2 = relu(agg1 @ W1 + b1)
    k_gather96<<<NN/8, 256, 0, stream>>>(Bf, csr2, base, degI, dinv, A);
    k_gemm<96,true ><<<NN/64, 256, 0, stream>>>(A, cW[side][1], cB[side][1], Bf);
    // layer 2 COMMUTED: agg2 = A_hat h2; pool first, then tiny GEMM on [NB,96]
    // mean = mean_pool(agg2) @ W2 + b2   (exact: no relu on layer 2, all linear)
    k_gather96<<<NN/8, 256, 0, stream>>>(Bf, csr2, base, degI, dinv, A);
    k_mean<<<NB, 128, 0, stream>>>(A, seg, poolT);
    k_gemm_pool<<<NB/64, 256, 0, stream>>>(poolT, cW[side][2], cB[side][2], seg, mean);
  }
  k_final<<<NB, 128, 0, stream>>>(meanP, meanD, attP, attD, lW0, lb0, lW1, lb1, out);
}

// Round 9
// 2126.627 us; speedup vs baseline: 1.2242x; 1.0746x over previous
//
#include <hip/hip_runtime.h>

#define NN 400000
#define EE 1600000
#define NB 8192

typedef float vf4 __attribute__((ext_vector_type(4)));
typedef float vf2 __attribute__((ext_vector_type(2)));

// ---------- segment bounds: start[b] = lower_bound(batch, b); batch is sorted ----------
__global__ void k_seg(const int* __restrict__ batch, int* __restrict__ start){
  int b = blockIdx.x*256 + threadIdx.x;
  if (b > NB) return;
  int lo = 0, hi = NN;
  while (lo < hi){ int mid = (lo+hi)>>1; if (batch[mid] < b) lo = mid+1; else hi = mid; }
  start[b] = lo;
}

// ---------- gate MLP as tiled GEMM: 64 rows/block, 4x4 micro-tile; 2nd layer fused ----------
__global__ __launch_bounds__(256) void k_gate(const float* __restrict__ x,
    const float* __restrict__ W1, const float* __restrict__ b1,
    const float* __restrict__ W2, const float* __restrict__ b2,
    float* __restrict__ g){
  __shared__ __align__(16) float sX[64*68];    // [k][r] transposed, pad 68
  __shared__ __align__(16) float sW[64*64];    // W1 [k][c]
  __shared__ float sB[128];      // b1 | W2
  __shared__ float sRed[64*17];  // per-row partials
  const int tid = threadIdx.x;
  const int r0 = blockIdx.x << 6;
  for (int i = tid; i < 4096; i += 256) sW[i] = W1[i];
  if (tid < 64) sB[tid] = b1[tid];
  else if (tid < 128) sB[tid] = W2[tid-64];
  for (int i = tid; i < 4096; i += 256){     // coalesced read of 64x64 tile
    int r = i >> 6, k = i & 63;
    sX[k*68 + r] = x[(size_t)r0*64 + i];
  }
  __syncthreads();
  const int tx = tid & 15;   // cols tx*4..+3
  const int ty = tid >> 4;   // rows ty*4..+3
  float acc[4][4];
  #pragma unroll
  for (int i = 0; i < 4; ++i)
    #pragma unroll
    for (int j = 0; j < 4; ++j) acc[i][j] = 0.f;
  for (int k = 0; k < 64; ++k){
    vf4 a = *(const vf4*)&sX[k*68 + ty*4];   // ds_read_b128 broadcast, conflict-free
    vf4 w = *(const vf4*)&sW[k*64 + tx*4];
    #pragma unroll
    for (int i = 0; i < 4; ++i)
      #pragma unroll
      for (int j = 0; j < 4; ++j)
        acc[i][j] = fmaf(a[i], w[j], acc[i][j]);
  }
  #pragma unroll
  for (int i = 0; i < 4; ++i){
    float p = 0.f;
    #pragma unroll
    for (int j = 0; j < 4; ++j){
      int c = tx*4 + j;
      p = fmaf(fmaxf(acc[i][j] + sB[c], 0.f), sB[64+c], p);
    }
    sRed[(ty*4+i)*17 + tx] = p;
  }
  __syncthreads();
  if (tid < 64){
    float s = 0.f;
    #pragma unroll
    for (int j = 0; j < 16; ++j) s += sRed[tid*17 + j];
    g[r0 + tid] = s + b2[0];
  }
}

// ---------- attention pool: one wave per graph (segments contiguous: batch sorted) ----------
__global__ __launch_bounds__(64) void k_att(const float* __restrict__ x, const float* __restrict__ g,
    const int* __restrict__ start, float* __restrict__ att){
  int b = blockIdx.x, lane = threadIdx.x;
  int s0 = start[b], s1 = start[b+1];
  if (s1 <= s0){ att[b*64+lane] = 0.f; return; }
  float m = -3.0e38f;
  for (int i = s0+lane; i < s1; i += 64) m = fmaxf(m, g[i]);
  #pragma unroll
  for (int off = 32; off; off >>= 1) m = fmaxf(m, __shfl_xor(m, off));
  float s = 0.f;
  for (int i = s0+lane; i < s1; i += 64) s += expf(g[i]-m);
  #pragma unroll
  for (int off = 32; off; off >>= 1) s += __shfl_xor(s, off);
  float acc = 0.f;
  for (int i = s0; i < s1; ++i)                       // lane = feature
    acc = fmaf(expf(g[i]-m), x[(size_t)i*64+lane], acc);
  att[b*64+lane] = acc / s;
}

// ---------- CSR build (per side, reused for all 3 layers) ----------
__global__ void k_zero(int* __restrict__ degI, int* __restrict__ gc){
  int i = blockIdx.x*256 + threadIdx.x;
  if (i < NN) degI[i] = 0;
  if (i == 0) *gc = 0;
}
__global__ void k_count(const int* __restrict__ dst, int* __restrict__ degI){
  int e = blockIdx.x*256 + threadIdx.x;
  if (e < EE) atomicAdd(&degI[dst[e]], 1);
}
// bucket allocation: wave-level prefix scan, one global atomic per wave
__global__ __launch_bounds__(256) void k_alloc(const int* __restrict__ degI, int* __restrict__ gc,
    int* __restrict__ base, int* __restrict__ cursor, float* __restrict__ dinv){
  int i = blockIdx.x*256 + threadIdx.x;
  int lane = threadIdx.x & 63;
  int d = (i < NN) ? degI[i] : 0;
  int incl = d;
  #pragma unroll
  for (int off = 1; off < 64; off <<= 1){
    int t = __shfl_up(incl, off);
    if (lane >= off) incl += t;
  }
  int waveTotal = __shfl(incl, 63);
  int wbase = 0;
  if (lane == 63) wbase = atomicAdd(gc, waveTotal);
  wbase = __shfl(wbase, 63);
  if (i < NN){
    int b = wbase + incl - d;   // exclusive offset within wave
    base[i] = b; cursor[i] = b;
    dinv[i] = 1.f / sqrtf((float)d + 1.f);   // +1 self loop
  }
}
// csr2[p] = {src, dinv[src]} -- weight folded in so gathers skip the dinv lookup
__global__ void k_fillcsr(const int* __restrict__ src, const int* __restrict__ dst,
                          const float* __restrict__ dinv,
                          int* __restrict__ cursor, int2* __restrict__ csr2){
  int e = blockIdx.x*256 + threadIdx.x;
  if (e >= EE) return;
  int s = src[e];
  int p = atomicAdd(&cursor[dst[e]], 1);
  csr2[p] = make_int2(s, __float_as_int(dinv[s]));
}

// ---------- tall-skinny GEMM: out[N,96] = act(in[N,K] @ W[K,96] + b) ----------
// R6-verified structure (153us): 256 threads, full-K staging, 4x6 micro-tile,
// vectorized LDS reads. 512-thread variant proven WORSE (R7: +60% issue cycles).
template<int K, bool RELU>
__global__ __launch_bounds__(256) void k_gemm(const float* __restrict__ in,
    const float* __restrict__ W, const float* __restrict__ bias, float* __restrict__ out){
  __shared__ __align__(16) float sIn[K*68];   // transposed [k][row], pad 68 (272B = 17*16)
  __shared__ __align__(16) float sW[K*96];
  __shared__ float sB[96];
  const int tid = threadIdx.x;
  const int r0 = blockIdx.x << 6;
  for (int i = tid; i < K*96; i += 256) sW[i] = W[i];
  if (tid < 96) sB[tid] = bias[tid];
  for (int i = tid; i < 64*K; i += 256){
    int r = i / K, k = i - r*K;
    sIn[k*68 + r] = in[(size_t)r0*K + i];
  }
  __syncthreads();
  const int tx = tid & 15;   // cols tx*6 .. +5
  const int ty = tid >> 4;   // rows ty*4 .. +3
  float acc[4][6];
  #pragma unroll
  for (int i = 0; i < 4; ++i)
    #pragma unroll
    for (int j = 0; j < 6; ++j) acc[i][j] = 0.f;
  for (int k = 0; k < K; ++k){
    vf4 a   = *(const vf4*)&sIn[k*68 + ty*4];       // b128, broadcast, conflict-free
    vf2 w01 = *(const vf2*)&sW[k*96 + tx*6];        // 3x b64, step 6 covers 32 banks
    vf2 w23 = *(const vf2*)&sW[k*96 + tx*6 + 2];
    vf2 w45 = *(const vf2*)&sW[k*96 + tx*6 + 4];
    float w[6] = {w01[0], w01[1], w23[0], w23[1], w45[0], w45[1]};
    #pragma unroll
    for (int i = 0; i < 4; ++i)
      #pragma unroll
      for (int j = 0; j < 6; ++j)
        acc[i][j] = fmaf(a[i], w[j], acc[i][j]);
  }
  #pragma unroll
  for (int i = 0; i < 4; ++i){
    size_t row = r0 + ty*4 + i;
    #pragma unroll
    for (int j = 0; j < 6; ++j){
      float v = acc[i][j] + sB[tx*6 + j];
      if (RELU) v = fmaxf(v, 0.f);
      out[row*96 + tx*6 + j] = v;
    }
  }
}

// ---------- pooled GEMM (layer-2 commute): mean [NB,96] @ W2 + b2, empty-seg masked ----------
__global__ __launch_bounds__(256) void k_gemm_pool(const float* __restrict__ in,
    const float* __restrict__ W, const float* __restrict__ bias,
    const int* __restrict__ start, float* __restrict__ out){
  constexpr int K = 96;
  __shared__ __align__(16) float sIn[K*68];
  __shared__ __align__(16) float sW[K*96];
  __shared__ float sB[96];
  const int tid = threadIdx.x;
  const int r0 = blockIdx.x << 6;
  for (int i = tid; i < K*96; i += 256) sW[i] = W[i];
  if (tid < 96) sB[tid] = bias[tid];
  for (int i = tid; i < 64*K; i += 256){
    int r = i / K, k = i - r*K;
    sIn[k*68 + r] = in[(size_t)r0*K + i];
  }
  __syncthreads();
  const int tx = tid & 15;
  const int ty = tid >> 4;
  float acc[4][6];
  #pragma unroll
  for (int i = 0; i < 4; ++i)
    #pragma unroll
    for (int j = 0; j < 6; ++j) acc[i][j] = 0.f;
  for (int k = 0; k < K; ++k){
    vf4 a   = *(const vf4*)&sIn[k*68 + ty*4];
    vf2 w01 = *(const vf2*)&sW[k*96 + tx*6];
    vf2 w23 = *(const vf2*)&sW[k*96 + tx*6 + 2];
    vf2 w45 = *(const vf2*)&sW[k*96 + tx*6 + 4];
    float w[6] = {w01[0], w01[1], w23[0], w23[1], w45[0], w45[1]};
    #pragma unroll
    for (int i = 0; i < 4; ++i)
      #pragma unroll
      for (int j = 0; j < 6; ++j)
        acc[i][j] = fmaf(a[i], w[j], acc[i][j]);
  }
  #pragma unroll
  for (int i = 0; i < 4; ++i){
    int row = r0 + ty*4 + i;
    bool nz = start[row+1] > start[row];
    #pragma unroll
    for (int j = 0; j < 6; ++j){
      float v = nz ? (acc[i][j] + sB[tx*6 + j]) : 0.f;
      out[(size_t)row*96 + tx*6 + j] = v;
    }
  }
}

// ---------- GCN aggregation (96 feats): agg[i] = di*(di*v[i] + sum_e w_e*v[src_e]) ----------
// Latency-bound -> 8-edge CLAMPED batch (R6 win): always issue 8 metadata + 8 vf4
// loads per iter; index clamped to cnt-1, weight zeroed for p>=cnt.
__global__ __launch_bounds__(256) void k_gather96(const float* __restrict__ xw,
    const int2* __restrict__ csr2, const int* __restrict__ base, const int* __restrict__ degI,
    const float* __restrict__ dinv, float* __restrict__ out){
  const int grp  = threadIdx.x >> 5;        // 8 nodes per block
  const int lane = threadIdx.x & 31;        // lanes 0..23 carry float4 features
  const int i = (blockIdx.x << 3) + grp;
  const bool act = lane < 24;
  const vf4* __restrict__ xw4 = (const vf4*)xw;
  const float di = dinv[i];
  const int b0 = base[i], cnt = degI[i];
  vf4 s = {0.f,0.f,0.f,0.f};
  if (act) s = di * xw4[(size_t)i*24 + lane];
  for (int t = 0; t < cnt; t += 8){
    int2 e[8]; float w[8];
    #pragma unroll
    for (int k = 0; k < 8; ++k){
      int p = t + k;
      int q = p < cnt ? p : cnt-1;          // clamp (cnt>=1 inside loop)
      e[k] = csr2[b0 + q];
      w[k] = (p < cnt) ? __int_as_float(e[k].y) : 0.f;
    }
    if (act){
      #pragma unroll
      for (int k = 0; k < 8; ++k){
        vf4 v = xw4[(size_t)e[k].x*24 + lane];
        s += w[k]*v;
      }
    }
  }
  if (act){
    vf4 r = di * s;
    ((vf4*)out)[(size_t)i*24 + lane] = r;
  }
}

// ---------- FUSED layer-2 gather + mean-pool: poolT[b] = mean_i(A_hat h2)[i in seg b] ----------
// A = A_hat h2 was materialized (153.6MB write) then streamed by k_mean (153.6MB read)
// just to produce 3MB of pooled rows. One block per graph: same clamped-8 per-node
// gather math as k_gather96, accumulate in regs, LDS cross-group reduce, write 96 floats.
__global__ __launch_bounds__(256) void k_poolgather(const float* __restrict__ h,
    const int2* __restrict__ csr2, const int* __restrict__ base, const int* __restrict__ degI,
    const float* __restrict__ dinv, const int* __restrict__ start, float* __restrict__ poolT){
  __shared__ __align__(16) float sAcc[8][96];
  const int b = blockIdx.x;
  const int s0 = start[b], s1 = start[b+1];
  const int grp = threadIdx.x >> 5, lane = threadIdx.x & 31;
  const bool act = lane < 24;
  const vf4* __restrict__ h4 = (const vf4*)h;
  vf4 acc = {0.f,0.f,0.f,0.f};
  for (int i = s0 + grp; i < s1; i += 8){
    const float di = dinv[i];
    const int b0 = base[i], cnt = degI[i];
    vf4 s = {0.f,0.f,0.f,0.f};
    if (act) s = di * h4[(size_t)i*24 + lane];
    for (int t = 0; t < cnt; t += 8){
      int2 e[8]; float w[8];
      #pragma unroll
      for (int k = 0; k < 8; ++k){
        int p = t + k;
        int q = p < cnt ? p : cnt-1;
        e[k] = csr2[b0 + q];
        w[k] = (p < cnt) ? __int_as_float(e[k].y) : 0.f;
      }
      if (act){
        #pragma unroll
        for (int k = 0; k < 8; ++k){
          vf4 v = h4[(size_t)e[k].x*24 + lane];
          s += w[k]*v;
        }
      }
    }
    acc += di * s;   // node i's row of A_hat h2
  }
  if (act) *(vf4*)&sAcc[grp][lane*4] = acc;
  __syncthreads();
  const int tid = threadIdx.x;
  if (tid < 96){
    float v = 0.f;
    #pragma unroll
    for (int g = 0; g < 8; ++g) v += sAcc[g][tid];
    poolT[(size_t)b*96 + tid] = v / fmaxf((float)(s1 - s0), 1.f);
  }
}

// ---------- GCN aggregation (64 feats, layer-0 reorder): agg0 = A_hat x ----------
__global__ __launch_bounds__(256) void k_gather64(const float* __restrict__ x,
    const int2* __restrict__ csr2, const int* __restrict__ base, const int* __restrict__ degI,
    const float* __restrict__ dinv, float* __restrict__ out){
  const int grp  = threadIdx.x >> 4;        // 16 nodes per block
  const int lane = threadIdx.x & 15;        // 16 lanes x float4 = 64 feats
  const int i = (blockIdx.x << 4) + grp;
  const vf4* __restrict__ x4 = (const vf4*)x;
  const float di = dinv[i];
  const int b0 = base[i], cnt = degI[i];
  vf4 s = di * x4[(size_t)i*16 + lane];
  for (int t = 0; t < cnt; t += 8){
    int2 e[8]; float w[8];
    #pragma unroll
    for (int k = 0; k < 8; ++k){
      int p = t + k;
      int q = p < cnt ? p : cnt-1;
      e[k] = csr2[b0 + q];
      w[k] = (p < cnt) ? __int_as_float(e[k].y) : 0.f;
    }
    #pragma unroll
    for (int k = 0; k < 8; ++k){
      vf4 v = x4[(size_t)e[k].x*16 + lane];
      s += w[k]*v;
    }
  }
  vf4 r = di * s;
  ((vf4*)out)[(size_t)i*16 + lane] = r;
}

// ---------- final MLP: relu(cat@W0+b0)@W1+b1 ; fp32 output ----------
__global__ __launch_bounds__(128) void k_final(const float* __restrict__ meanP, const float* __restrict__ meanD,
    const float* __restrict__ attP, const float* __restrict__ attD,
    const float* __restrict__ W0, const float* __restrict__ b0,
    const float* __restrict__ W1, const float* __restrict__ b1,
    float* __restrict__ out){
  __shared__ float cat[320];
  __shared__ float hb[96];
  int b = blockIdx.x, tid = threadIdx.x;
  if (tid < 96){ cat[tid] = meanP[b*96+tid]; cat[96+tid] = meanD[b*96+tid]; }
  if (tid < 64){ cat[192+tid] = attP[b*64+tid]; cat[256+tid] = attD[b*64+tid]; }
  __syncthreads();
  if (tid < 96){
    float acc = b0[tid];
    for (int k = 0; k < 320; ++k) acc = fmaf(cat[k], W0[k*96+tid], acc);
    hb[tid] = fmaxf(acc, 0.f) * W1[tid];
  }
  __syncthreads();
  if (tid == 0){
    float y = b1[0];
    for (int j = 0; j < 96; ++j) y += hb[j];
    out[b] = y;
  }
}

extern "C" void kernel_launch(void* const* d_in, const int* in_sizes, int n_in,
                              void* d_out, int out_size, void* d_ws, size_t ws_size,
                              hipStream_t stream){
  const float* x_p = (const float*)d_in[0];
  const float* x_d = (const float*)d_in[1];
  const int* ei_p = (const int*)d_in[4];    // [2,E]: row0 src, row1 dst
  const int* ei_d = (const int*)d_in[5];
  const int* batch_p = (const int*)d_in[6];
  const int* batch_d = (const int*)d_in[7];
  const float* gW1 = (const float*)d_in[8];
  const float* gb1 = (const float*)d_in[9];
  const float* gW2 = (const float*)d_in[10];
  const float* gb2 = (const float*)d_in[11];
  const float* cW[2][3] = {{(const float*)d_in[12],(const float*)d_in[14],(const float*)d_in[16]},
                           {(const float*)d_in[18],(const float*)d_in[20],(const float*)d_in[22]}};
  const float* cB[2][3] = {{(const float*)d_in[13],(const float*)d_in[15],(const float*)d_in[17]},
                           {(const float*)d_in[19],(const float*)d_in[21],(const float*)d_in[23]}};
  const float* lW0 = (const float*)d_in[24];
  const float* lb0 = (const float*)d_in[25];
  const float* lW1 = (const float*)d_in[26];
  const float* lb1 = (const float*)d_in[27];
  float* out = (float*)d_out;

  // workspace carve-up (~366 MB)
  float* fws = (float*)d_ws;
  size_t off = 0;
  float* A     = fws + off; off += (size_t)NN*96;   // agg buffer (64- or 96-dim)
  float* Bf    = fws + off; off += (size_t)NN*96;   // hidden buffer
  float* dinv  = fws + off; off += NN;
  float* g     = fws + off; off += NN;
  float* attP  = fws + off; off += (size_t)NB*64;
  float* attD  = fws + off; off += (size_t)NB*64;
  float* meanP = fws + off; off += (size_t)NB*96;
  float* meanD = fws + off; off += (size_t)NB*96;
  float* poolT = fws + off; off += (size_t)NB*96;   // pooled pre-W2 buffer
  int2* csr2  = (int2*)(fws + off);                 // 8-byte aligned (off is even)
  int* iws = (int*)(csr2 + EE);
  int* segP   = iws;             iws += NB+1;
  int* segD   = iws;             iws += NB+1;
  int* degI   = iws;             iws += NN;
  int* base   = iws;             iws += NN;
  int* cursor = iws;             iws += NN;
  int* gc     = iws;             iws += 1;

  k_seg<<<(NB+1+255)/256, 256, 0, stream>>>(batch_p, segP);
  k_seg<<<(NB+1+255)/256, 256, 0, stream>>>(batch_d, segD);

  for (int side = 0; side < 2; ++side){
    const float* x  = side ? x_d : x_p;
    const int* src = side ? ei_d : ei_p;
    const int* dst = src + EE;
    const int* seg = side ? segD : segP;
    float* att  = side ? attD : attP;
    float* mean = side ? meanD : meanP;

    k_gate<<<NN/64, 256, 0, stream>>>(x, gW1, gb1, gW2, gb2, g);
    k_att<<<NB, 64, 0, stream>>>(x, g, seg, att);

    k_zero   <<<(NN+255)/256, 256, 0, stream>>>(degI, gc);
    k_count  <<<(EE+255)/256, 256, 0, stream>>>(dst, degI);
    k_alloc  <<<(NN+255)/256, 256, 0, stream>>>(degI, gc, base, cursor, dinv);
    k_fillcsr<<<(EE+255)/256, 256, 0, stream>>>(src, dst, dinv, cursor, csr2);

    // layer 0 reordered: agg0 = A_hat x (64-dim), then h1 = relu(agg0 @ W0 + b0)
    k_gather64<<<NN/16, 256, 0, stream>>>(x, csr2, base, degI, dinv, A);
    k_gemm<64,true ><<<NN/64, 256, 0, stream>>>(A, cW[side][0], cB[side][0], Bf);
    // layer 1: agg1 = A_hat h1, h2 = relu(agg1 @ W1 + b1)
    k_gather96<<<NN/8, 256, 0, stream>>>(Bf, csr2, base, degI, dinv, A);
    k_gemm<96,true ><<<NN/64, 256, 0, stream>>>(A, cW[side][1], cB[side][1], Bf);
    // layer 2 COMMUTED+FUSED: poolT = mean_pool(A_hat h2) computed directly
    // (no [N,96] materialization), then mean = poolT @ W2 + b2 on [NB,96]
    k_poolgather<<<NB, 256, 0, stream>>>(Bf, csr2, base, degI, dinv, seg, poolT);
    k_gemm_pool<<<NB/64, 256, 0, stream>>>(poolT, cW[side][2], cB[side][2], seg, mean);
  }
  k_final<<<NB, 128, 0, stream>>>(meanP, meanD, attP, attD, lW0, lb0, lW1, lb1, out);
}